// Round 3
// baseline (633.591 us; speedup 1.0000x reference)
//
#include <hip/hip_runtime.h>

#define BB 64
#define SS 2048
#define DD 1024
#define SCHUNK 64
#define NC (SS / SCHUNK)   // 32 s-chunks

typedef float f32x4 __attribute__((ext_vector_type(4)));

// Pass 1: per (b, s-chunk) masked partial sum over D (skips mask==0 rows,
// ~50% of HBM traffic). vs round 2 (null occupancy result): attack the
// address path and load pipeline instead.
//  - row indices live in ONE per-lane register; the hot loop broadcasts
//    them with readlane -> row offset is wave-uniform (SGPR add), the only
//    per-lane address component is a loop-invariant VGPR (t*16).
//  - 16 dwordx4 loads in flight per wave (was 8), no LDS / no VALU mul in
//    the address chain, so the compiler can hoist the next burst's loads
//    above the current burst's accumulate chain.
//  - plain (cached) loads: drop the nontemporal hint, matching the 6.4 TB/s
//    fill kernels' plain access.
__global__ __launch_bounds__(256) void ep_partial(
    const float* __restrict__ hidden, const int* __restrict__ mask,
    float* __restrict__ wsm, float* __restrict__ wscnt)
{
    const int b    = blockIdx.x;
    const int c    = blockIdx.y;
    const int t    = threadIdx.x;
    const int lane = t & 63;

    __shared__ unsigned char sidx[SCHUNK];
    __shared__ int s_n;

    // wave 0 classifies this chunk's 64 mask entries
    if (t < 64) {
        const int m = (mask[b * SS + c * SCHUNK + t] != 0) ? 1 : 0;
        const unsigned long long bal = __ballot(m);
        const int pre = __popcll(bal & ((1ull << lane) - 1ull));
        if (m) sidx[pre] = (unsigned char)t;
        if (t == 0) s_n = __popcll(bal);
    }
    __syncthreads();
    const int n1 = s_n;

    // lane l of every wave holds the byte offset of compacted row l
    const unsigned rowoff = (unsigned)sidx[lane] * 4096u;   // garbage beyond n1, never used

    const char* base = (const char*)hidden
                     + (size_t)(b * SS + c * SCHUNK) * DD * sizeof(float);
    const unsigned toff = (unsigned)t * 16u;                // per-lane, loop-invariant

#define ROW(J)  (base + (unsigned)__builtin_amdgcn_readlane((int)rowoff, i + (J)) + toff)

    f32x4 am = {0.f, 0.f, 0.f, 0.f};

    int i = 0;
    for (; i + 16 <= n1; i += 16) {
        f32x4 v0  = *(const f32x4*)ROW(0);
        f32x4 v1  = *(const f32x4*)ROW(1);
        f32x4 v2  = *(const f32x4*)ROW(2);
        f32x4 v3  = *(const f32x4*)ROW(3);
        f32x4 v4  = *(const f32x4*)ROW(4);
        f32x4 v5  = *(const f32x4*)ROW(5);
        f32x4 v6  = *(const f32x4*)ROW(6);
        f32x4 v7  = *(const f32x4*)ROW(7);
        f32x4 v8  = *(const f32x4*)ROW(8);
        f32x4 v9  = *(const f32x4*)ROW(9);
        f32x4 v10 = *(const f32x4*)ROW(10);
        f32x4 v11 = *(const f32x4*)ROW(11);
        f32x4 v12 = *(const f32x4*)ROW(12);
        f32x4 v13 = *(const f32x4*)ROW(13);
        f32x4 v14 = *(const f32x4*)ROW(14);
        f32x4 v15 = *(const f32x4*)ROW(15);
        // ascending s-order, single accumulator (bitwise-stable vs round 2)
        am += v0;  am += v1;  am += v2;  am += v3;
        am += v4;  am += v5;  am += v6;  am += v7;
        am += v8;  am += v9;  am += v10; am += v11;
        am += v12; am += v13; am += v14; am += v15;
    }
    for (; i + 4 <= n1; i += 4) {
        f32x4 v0 = *(const f32x4*)ROW(0);
        f32x4 v1 = *(const f32x4*)ROW(1);
        f32x4 v2 = *(const f32x4*)ROW(2);
        f32x4 v3 = *(const f32x4*)ROW(3);
        am += v0; am += v1; am += v2; am += v3;
    }
    for (; i < n1; ++i)
        am += *(const f32x4*)ROW(0);
#undef ROW

    reinterpret_cast<f32x4*>(wsm)[(size_t)(b * NC + c) * (DD / 4) + t] = am;
    if (t == 0) wscnt[b * NC + c] = (float)n1;
}

// Pass 2: 256 blocks (b x quarter-of-D), one wave each. Sums the 32 chunk
// partials + chunk counts, divides. cnt==0 fallback (never taken on this
// data) recomputes the full mean directly from hidden.
__global__ __launch_bounds__(64) void ep_finalize(
    const float* __restrict__ wsm, const float* __restrict__ wscnt,
    const float* __restrict__ hidden, float* __restrict__ out)
{
    const int b    = blockIdx.x;
    const int q    = blockIdx.y;            // D quarter
    const int lane = threadIdx.x;           // 0..63
    const int d4   = q * 64 + lane;         // float4 column in [0,256)

    float cnt = 0.f;
    #pragma unroll
    for (int c = 0; c < NC; ++c) cnt += wscnt[b * NC + c];   // uniform -> s_loads

    const f32x4* pm = reinterpret_cast<const f32x4*>(wsm)
                      + (size_t)b * NC * (DD / 4) + d4;
    f32x4 am = {0.f, 0.f, 0.f, 0.f};
    #pragma unroll
    for (int c = 0; c < NC; ++c) am += pm[(size_t)c * (DD / 4)];

    f32x4 r;
    if (cnt > 0.f) {
        r.x = am.x / cnt; r.y = am.y / cnt; r.z = am.z / cnt; r.w = am.w / cnt;
    } else {
        // all-zero mask row: full mean (cold path, kept for correctness)
        const f32x4* hp = reinterpret_cast<const f32x4*>(hidden)
                          + (size_t)b * SS * (DD / 4) + d4;
        f32x4 af = {0.f, 0.f, 0.f, 0.f};
        for (int s = 0; s < SS; ++s) af += hp[(size_t)s * (DD / 4)];
        const float invS = 1.0f / (float)SS;
        r.x = af.x * invS; r.y = af.y * invS; r.z = af.z * invS; r.w = af.w * invS;
    }
    reinterpret_cast<f32x4*>(out)[(size_t)b * (DD / 4) + d4] = r;
}

extern "C" void kernel_launch(void* const* d_in, const int* in_sizes, int n_in,
                              void* d_out, int out_size, void* d_ws, size_t ws_size,
                              hipStream_t stream) {
    const float* hidden = (const float*)d_in[0];
    const int*   mask   = (const int*)d_in[1];
    float*       out    = (float*)d_out;

    // workspace: [B*NC*D] masked partials (8 MiB) | [B*NC] chunk counts
    float* wsm   = (float*)d_ws;
    float* wscnt = wsm + (size_t)BB * NC * DD;

    ep_partial<<<dim3(BB, NC), 256, 0, stream>>>(hidden, mask, wsm, wscnt);
    ep_finalize<<<dim3(BB, 4), 64, 0, stream>>>(wsm, wscnt, hidden, out);
}

// Round 4
// 613.981 us; speedup vs baseline: 1.0319x; 1.0319x over previous
//
#include <hip/hip_runtime.h>

#define BB 64
#define SS 2048
#define DD 1024
#define QC 8               // s-chunks per batch
#define RCH (SS / QC)      // 256 rows per chunk = 1 MiB contiguous per block

typedef float f32x4 __attribute__((ext_vector_type(4)));

// Pass 1: per (b, s-chunk) masked partial sum over D, skipping mask==0 rows.
// vs rounds 1-3 (all ~3 TB/s read): those used 1024-2048 co-resident blocks
// each walking a private 128-512 KiB region -> ~2048 scattered 4 KiB
// requests in flight device-wide, thrashing DRAM row activation. This
// version uses 512 blocks (2/CU), each sweeping ONE contiguous 1 MiB run of
// 256 rows, 4 waves in lockstep, 16 loads in flight per wave -- the
// grid-stride-like contiguous instantaneous footprint that the 6.4 TB/s
// fill kernels have.
__global__ __launch_bounds__(256) void ep_partial(
    const float* __restrict__ hidden, const int* __restrict__ mask,
    float* __restrict__ wsm, float* __restrict__ wscnt)
{
    const int b    = blockIdx.x;
    const int q    = blockIdx.y;
    const int s0   = q * RCH;
    const int t    = threadIdx.x;
    const int w    = t >> 6;
    const int lane = t & 63;

    __shared__ unsigned char sidx[RCH];   // compacted row indices (0..255)
    __shared__ int s_wcnt[4];

    // all 4 waves classify their 64 rows; cross-wave prefix via counts
    const int m = (mask[b * SS + s0 + t] != 0) ? 1 : 0;
    const unsigned long long bal = __ballot(m);
    const int pre = __popcll(bal & ((1ull << lane) - 1ull));
    if (lane == 0) s_wcnt[w] = __popcll(bal);
    __syncthreads();
    int cbase = 0;
    #pragma unroll
    for (int j = 0; j < 4; ++j) cbase += (j < w) ? s_wcnt[j] : 0;
    const int n1 = s_wcnt[0] + s_wcnt[1] + s_wcnt[2] + s_wcnt[3];
    if (m) sidx[cbase + pre] = (unsigned char)t;
    __syncthreads();

    // thread t owns d = 4t..4t+3; rows ascend => bitwise-stable summation
    const char* base = (const char*)hidden
                     + (size_t)(b * SS + s0) * DD * sizeof(float);
    const unsigned toff = (unsigned)t * 16u;

#define LD(J) __builtin_nontemporal_load( \
        (const f32x4*)(base + (unsigned)sidx[i + (J)] * 4096u + toff))

    f32x4 am = {0.f, 0.f, 0.f, 0.f};

    int i = 0;
    for (; i + 16 <= n1; i += 16) {
        f32x4 v0  = LD(0);  f32x4 v1  = LD(1);
        f32x4 v2  = LD(2);  f32x4 v3  = LD(3);
        f32x4 v4  = LD(4);  f32x4 v5  = LD(5);
        f32x4 v6  = LD(6);  f32x4 v7  = LD(7);
        f32x4 v8  = LD(8);  f32x4 v9  = LD(9);
        f32x4 v10 = LD(10); f32x4 v11 = LD(11);
        f32x4 v12 = LD(12); f32x4 v13 = LD(13);
        f32x4 v14 = LD(14); f32x4 v15 = LD(15);
        am += v0;  am += v1;  am += v2;  am += v3;
        am += v4;  am += v5;  am += v6;  am += v7;
        am += v8;  am += v9;  am += v10; am += v11;
        am += v12; am += v13; am += v14; am += v15;
    }
    for (; i + 4 <= n1; i += 4) {
        f32x4 v0 = LD(0); f32x4 v1 = LD(1);
        f32x4 v2 = LD(2); f32x4 v3 = LD(3);
        am += v0; am += v1; am += v2; am += v3;
    }
    for (; i < n1; ++i)
        am += LD(0);
#undef LD

    reinterpret_cast<f32x4*>(wsm)[(size_t)(b * QC + q) * (DD / 4) + t] = am;
    if (t == 0) wscnt[b * QC + q] = (float)n1;
}

// Pass 2: 256 blocks (b x quarter-of-D), one wave each. Sums the 8 chunk
// partials + chunk counts, divides. cnt==0 fallback (never taken on this
// data) recomputes the full mean directly from hidden.
__global__ __launch_bounds__(64) void ep_finalize(
    const float* __restrict__ wsm, const float* __restrict__ wscnt,
    const float* __restrict__ hidden, float* __restrict__ out)
{
    const int b    = blockIdx.x;
    const int qd   = blockIdx.y;            // D quarter
    const int lane = threadIdx.x;           // 0..63
    const int d4   = qd * 64 + lane;        // float4 column in [0,256)

    float cnt = 0.f;
    #pragma unroll
    for (int c = 0; c < QC; ++c) cnt += wscnt[b * QC + c];   // uniform -> s_loads

    const f32x4* pm = reinterpret_cast<const f32x4*>(wsm)
                      + (size_t)b * QC * (DD / 4) + d4;
    f32x4 am = {0.f, 0.f, 0.f, 0.f};
    #pragma unroll
    for (int c = 0; c < QC; ++c) am += pm[(size_t)c * (DD / 4)];

    f32x4 r;
    if (cnt > 0.f) {
        r.x = am.x / cnt; r.y = am.y / cnt; r.z = am.z / cnt; r.w = am.w / cnt;
    } else {
        // all-zero mask row: full mean (cold path, kept for correctness)
        const f32x4* hp = reinterpret_cast<const f32x4*>(hidden)
                          + (size_t)b * SS * (DD / 4) + d4;
        f32x4 af = {0.f, 0.f, 0.f, 0.f};
        for (int s = 0; s < SS; ++s) af += hp[(size_t)s * (DD / 4)];
        const float invS = 1.0f / (float)SS;
        r.x = af.x * invS; r.y = af.y * invS; r.z = af.z * invS; r.w = af.w * invS;
    }
    reinterpret_cast<f32x4*>(out)[(size_t)b * (DD / 4) + d4] = r;
}

extern "C" void kernel_launch(void* const* d_in, const int* in_sizes, int n_in,
                              void* d_out, int out_size, void* d_ws, size_t ws_size,
                              hipStream_t stream) {
    const float* hidden = (const float*)d_in[0];
    const int*   mask   = (const int*)d_in[1];
    float*       out    = (float*)d_out;

    // workspace: [B*QC*D] masked partials (2 MiB) | [B*QC] chunk counts
    float* wsm   = (float*)d_ws;
    float* wscnt = wsm + (size_t)BB * QC * DD;

    ep_partial<<<dim3(BB, QC), 256, 0, stream>>>(hidden, mask, wsm, wscnt);
    ep_finalize<<<dim3(BB, 4), 64, 0, stream>>>(wsm, wscnt, hidden, out);
}

// Round 5
// 609.419 us; speedup vs baseline: 1.0397x; 1.0075x over previous
//
#include <hip/hip_runtime.h>

#define BB 64
#define SS 2048
#define DD 1024
#define SCHUNK 128
#define NC (SS / SCHUNK)   // 16 s-chunks

typedef float f32x4 __attribute__((ext_vector_type(4)));

// FINAL KERNEL (round-1 variant, best measured: 603 µs, absmax 6.1e-5).
//
// Pass 1: per (b, s-chunk) masked partial sum over D.
// Rows with mask==0 contribute exactly 0.0f to the masked sum, and the
// full-sum fallback is only consumed when cnt==0 (never on this data,
// handled in pass 2) -> SKIP ~50% of the 512 MiB hidden read. Row indices
// with m==1 are compacted into LDS via wave ballots; the hot loop streams
// only selected 4-KiB rows, 8 loads in flight per wave, ascending s-order.
//
// Perf note (rounds 2-4): occupancy doubling, SGPR-scalarized addressing,
// dropping `nt`, and contiguous-1MiB-per-block tiling are ALL null -- this
// kernel runs at the box's demonstrated HBM *read* ceiling (~3.2 TB/s;
// write-only fills do 6.4, copy does ~3.15 each way). Do not expect tiling
// changes to move it.
__global__ __launch_bounds__(256) void ep_partial(
    const float* __restrict__ hidden, const int* __restrict__ mask,
    float* __restrict__ wsm, float* __restrict__ wscnt)
{
    const int b  = blockIdx.x;
    const int c  = blockIdx.y;
    const int s0 = c * SCHUNK;
    const int t  = threadIdx.x;

    __shared__ unsigned char sidx[SCHUNK];
    __shared__ int s_wcnt[2];
    __shared__ int s_n;

    // --- ballot compaction: waves 0,1 classify the 128 mask entries ---
    const int lane = t & 63;
    const int w    = t >> 6;
    int m = 0;
    if (t < SCHUNK) m = (mask[b * SS + s0 + t] != 0) ? 1 : 0;
    const unsigned long long bal = __ballot(m);          // waves 2,3: bal==0
    const int pre = __popcll(bal & ((1ull << lane) - 1ull));
    if (t < SCHUNK && lane == 0) s_wcnt[w] = __popcll(bal);
    __syncthreads();
    if (m) sidx[(w ? s_wcnt[0] : 0) + pre] = (unsigned char)t;
    if (t == 0) s_n = s_wcnt[0] + s_wcnt[1];
    __syncthreads();
    const int n1 = s_n;

    // --- stream only the selected rows; thread t owns float4 column t ---
    const f32x4* hp = reinterpret_cast<const f32x4*>(
        hidden + ((size_t)b * SS + s0) * DD) + t;

    f32x4 am = {0.f, 0.f, 0.f, 0.f};

    int i = 0;
    for (; i + 8 <= n1; i += 8) {
        const int i0 = sidx[i + 0], i1 = sidx[i + 1];
        const int i2 = sidx[i + 2], i3 = sidx[i + 3];
        const int i4 = sidx[i + 4], i5 = sidx[i + 5];
        const int i6 = sidx[i + 6], i7 = sidx[i + 7];
        f32x4 v0 = __builtin_nontemporal_load(hp + (size_t)i0 * (DD / 4));
        f32x4 v1 = __builtin_nontemporal_load(hp + (size_t)i1 * (DD / 4));
        f32x4 v2 = __builtin_nontemporal_load(hp + (size_t)i2 * (DD / 4));
        f32x4 v3 = __builtin_nontemporal_load(hp + (size_t)i3 * (DD / 4));
        f32x4 v4 = __builtin_nontemporal_load(hp + (size_t)i4 * (DD / 4));
        f32x4 v5 = __builtin_nontemporal_load(hp + (size_t)i5 * (DD / 4));
        f32x4 v6 = __builtin_nontemporal_load(hp + (size_t)i6 * (DD / 4));
        f32x4 v7 = __builtin_nontemporal_load(hp + (size_t)i7 * (DD / 4));
        // single accumulator, ascending order: bitwise-identical to the
        // original mask-FMA accumulation (adding exact zeros).
        am += v0; am += v1; am += v2; am += v3;
        am += v4; am += v5; am += v6; am += v7;
    }
    for (; i < n1; ++i)
        am += __builtin_nontemporal_load(hp + (size_t)sidx[i] * (DD / 4));

    reinterpret_cast<f32x4*>(wsm)[(size_t)(b * NC + c) * (DD / 4) + t] = am;
    if (t == 0) wscnt[b * NC + c] = (float)n1;
}

// Pass 2: 256 blocks (b x quarter-of-D), one wave each. Sums the 16 chunk
// partials + chunk counts, divides. cnt==0 fallback (never taken on this
// data) recomputes the full mean directly from hidden.
__global__ __launch_bounds__(64) void ep_finalize(
    const float* __restrict__ wsm, const float* __restrict__ wscnt,
    const float* __restrict__ hidden, float* __restrict__ out)
{
    const int b    = blockIdx.x;
    const int q    = blockIdx.y;            // D quarter
    const int lane = threadIdx.x;           // 0..63
    const int d4   = q * 64 + lane;         // float4 column in [0,256)

    float cnt = 0.f;
    #pragma unroll
    for (int c = 0; c < NC; ++c) cnt += wscnt[b * NC + c];   // uniform -> s_loads

    const f32x4* pm = reinterpret_cast<const f32x4*>(wsm)
                      + (size_t)b * NC * (DD / 4) + d4;
    f32x4 am = {0.f, 0.f, 0.f, 0.f};
    #pragma unroll
    for (int c = 0; c < NC; ++c) am += pm[(size_t)c * (DD / 4)];

    f32x4 r;
    if (cnt > 0.f) {
        r.x = am.x / cnt; r.y = am.y / cnt; r.z = am.z / cnt; r.w = am.w / cnt;
    } else {
        // all-zero mask row: full mean (cold path, kept for correctness)
        const f32x4* hp = reinterpret_cast<const f32x4*>(hidden)
                          + (size_t)b * SS * (DD / 4) + d4;
        f32x4 af = {0.f, 0.f, 0.f, 0.f};
        for (int s = 0; s < SS; ++s) af += hp[(size_t)s * (DD / 4)];
        const float invS = 1.0f / (float)SS;
        r.x = af.x * invS; r.y = af.y * invS; r.z = af.z * invS; r.w = af.w * invS;
    }
    reinterpret_cast<f32x4*>(out)[(size_t)b * (DD / 4) + d4] = r;
}

extern "C" void kernel_launch(void* const* d_in, const int* in_sizes, int n_in,
                              void* d_out, int out_size, void* d_ws, size_t ws_size,
                              hipStream_t stream) {
    const float* hidden = (const float*)d_in[0];
    const int*   mask   = (const int*)d_in[1];
    float*       out    = (float*)d_out;

    // workspace: [B*NC*D] masked partials (4 MiB) | [B*NC] chunk counts
    float* wsm   = (float*)d_ws;
    float* wscnt = wsm + (size_t)BB * NC * DD;

    ep_partial<<<dim3(BB, NC), 256, 0, stream>>>(hidden, mask, wsm, wscnt);
    ep_finalize<<<dim3(BB, 4), 64, 0, stream>>>(wsm, wscnt, hidden, out);
}